// Round 10
// baseline (168.576 us; speedup 1.0000x reference)
//
#include <hip/hip_runtime.h>

// PLELayer round-27: r24 revert (EPB=128/NT=512 proven best; EPB=64
// falsified in r26: 53-55 vs 49.4) + cross-barrier weight prefetch:
// phase-3's W1F1C K16 frags (16 VGPR) are loaded BEFORE the phase-2
// barrier (wsU is constant; compiler can't hoist loads past the fence,
// so do it manually) and carried in registers through the gate phase.
// VGPR budget: 6 waves/SIMD (LDS-bound 3 blk/CU) tolerates <=80;
// r24=56, +16 = ~72. Tripwires: VGPR>80 (residency loss), WRITE>1536
// (spill). Predict dur 47.5-49.5; if flat vs r24 -> structural plateau
// (all pipes <40%, wall = phase-dependency latency).

#define NT 512
#define EPB 128
#define XST 36   // xsA/l1in stride in u32 (mult of 4 -> aligned; s4=9 odd)

typedef unsigned short u16;
typedef unsigned int u32;
typedef __fp16 hv2 __attribute__((ext_vector_type(2)));
typedef __fp16 half4 __attribute__((ext_vector_type(4)));
typedef __fp16 half8 __attribute__((ext_vector_type(8)));
typedef __attribute__((ext_vector_type(4))) float floatx4;

__device__ __forceinline__ u32 pkh2(float a, float b){
  hv2 v = __builtin_amdgcn_cvt_pkrtz(a, b);
  u32 r; __builtin_memcpy(&r, &v, 4); return r;
}
__device__ __forceinline__ hv2 u2h(u32 w){ hv2 v; __builtin_memcpy(&v, &w, 4); return v; }
__device__ __forceinline__ u32 h2u(hv2 v){ u32 w; __builtin_memcpy(&w, &v, 4); return w; }
__device__ __forceinline__ float dot2(u32 a, u32 b, float c){
  return __builtin_amdgcn_fdot2(u2h(a), u2h(b), c, false);
}
// pack two f32 then relu in f16 (v_cvt_pkrtz + v_pk_max_f16)
__device__ __forceinline__ u32 pkrelu(float a, float b){
  hv2 v = __builtin_amdgcn_cvt_pkrtz(a, b);
  hv2 z = (hv2){(__fp16)0.f, (__fp16)0.f};
  return h2u(__builtin_elementwise_max(v, z));
}

// ---- ws layout (u32 offsets) ----
#define W1F0 0          // [16u][2s][4t][64l][4] = 32768 (s=0,1 K32 frags)
#define W1F0C 32768     // [16u][4t][64l][2]     =  8192 (s=2 K16: k=64+q*4+2j2(+b); k72=b1; 0-pad)
#define W2F0 40960      // [16u][2ks][64l][4]    =  8192 (h'(q,ks,j) perm)
#define W1F1C 49152     // [15u][4t][64l][2]     =  7680 (K16: k=q*4+2j2(+b); k8=b1; 0-pad)
#define W2F1 56832      // [15u][2ks][64l][4]    =  7680 (h' perm)
#define OFF_b2P0 64512  // [16][16] cols 8..15 zero
#define OFF_b2P1 64768  // [15][16] cols 8..15 zero
#define OFF_G0W3 65008  // [3t][6m][4jp] packed f16 pairs = 72
#define OFF_SG0W3 65080 // [12m][4jp] = 48
#define OFF_G1W3 65128  // [3t][6m][4jp] = 72
#define OFF_Tb 65200    // [3]
#define OFF_TWH 65203   // [3][4] u32: packed f16 pairs of tower_W
#define CVT_TOTAL 65215

struct PSrc { const float* p[33]; };

__global__ void cvt_kernel(PSrc S, u32* __restrict__ wsU, float* __restrict__ wsF){
  int i = blockIdx.x*256 + threadIdx.x;
  if (i >= CVT_TOTAL) return;
  if (i < 32768){  // W1F0 s=0,1: lane holds W1[k=s*32+q*8+2j2(+b)][h=t*16+c16]
    int j2 = i & 3, l = (i>>2)&63, tt = (i>>8)&3;
    int rest = i >> 10; int s = rest & 1, u = rest >> 1;
    int k0 = s*32 + (l>>4)*8 + 2*j2;
    int h  = tt*16 + (l&15);
    const float* src = (u<9)  ? S.p[0]  + (u*72)*64
                     : (u<12) ? S.p[4]  + ((u-9)*72)*64
                     : (u<15) ? S.p[8]  + ((u-12)*72)*64
                              : S.p[13];
    wsU[i] = pkh2(src[k0*64 + h], src[(k0+1)*64 + h]);   // k0+1 <= 63 < 72
    return;
  }
  i -= 32768;
  if (i < 8192){   // W1F0C (s=2, K16): k0 = 64 + q*4 + 2*j2; k72 = bias; >72 -> 0
    int j2 = i & 1, l = (i>>1)&63, tt = (i>>7)&3, u = i>>9;
    int k0 = 64 + (l>>4)*4 + 2*j2;
    int h  = tt*16 + (l&15);
    const float* src = (u<9)  ? S.p[0]  + (u*72)*64
                     : (u<12) ? S.p[4]  + ((u-9)*72)*64
                     : (u<15) ? S.p[8]  + ((u-12)*72)*64
                              : S.p[13];
    const float* bsrc = (u<9)  ? S.p[1] + u*64
                      : (u<12) ? S.p[5] + (u-9)*64
                      : (u<15) ? S.p[9] + (u-12)*64
                               : S.p[14];
    float lo = (k0 < 72) ? src[k0*64 + h] : ((k0==72) ? bsrc[h] : 0.f);
    float hi = (k0+1 < 72) ? src[(k0+1)*64 + h] : 0.f;
    wsU[W1F0C + i] = pkh2(lo, hi);
    return;
  }
  i -= 8192;
  if (i < 8192){   // W2F0: W2[h'(q,ks,j)][n=l&15], n>=8 -> 0
    int j2 = i & 3, l = (i>>2)&63, ks = (i>>8)&1, u = i>>9;
    int q = l >> 4, n = l & 15;
    int h0 = (2*ks + ((2*j2)>>2))*16 + q*4 + ((2*j2)&3);
    const float* src = (u<9)  ? S.p[2]  + u*512
                     : (u<12) ? S.p[6]  + (u-9)*512
                     : (u<15) ? S.p[10] + (u-12)*512
                              : S.p[15];
    float lo = (n<8) ? src[h0*8 + n] : 0.f;
    float hi = (n<8) ? src[(h0+1)*8 + n] : 0.f;
    wsU[W2F0 + i] = pkh2(lo, hi);
    return;
  }
  i -= 8192;
  if (i < 7680){   // W1F1C (K16): k0 = q*4 + 2*j2; k8 = bias; >8 -> 0
    int j2 = i & 1, l = (i>>1)&63, tt = (i>>7)&3, u = i>>9;
    int k0 = (l>>4)*4 + 2*j2;
    int n = tt*16 + (l&15);
    const float* src = (u<9) ? S.p[18] + (u*8)*64
                     : (u<12) ? S.p[22] + ((u-9)*8)*64
                              : S.p[26] + ((u-12)*8)*64;
    const float* bsrc = (u<9) ? S.p[19] + u*64
                      : (u<12) ? S.p[23] + (u-9)*64
                               : S.p[27] + (u-12)*64;
    float lo = (k0 < 8) ? src[k0*64 + n] : ((k0==8) ? bsrc[n] : 0.f);
    float hi = (k0+1 < 8) ? src[(k0+1)*64 + n] : 0.f;
    wsU[W1F1C + i] = pkh2(lo, hi);
    return;
  }
  i -= 7680;
  if (i < 7680){   // W2F1: h'(q,ks,j) permutation, n>=8 -> 0
    int j2 = i & 3, l = (i>>2)&63, ks = (i>>8)&1, u = i>>9;
    int q = l >> 4, n = l & 15;
    int h0 = (2*ks + ((2*j2)>>2))*16 + q*4 + ((2*j2)&3);
    const float* src = (u<9) ? S.p[20] + u*512
                     : (u<12) ? S.p[24] + (u-9)*512
                              : S.p[28] + (u-12)*512;
    float lo = (n<8) ? src[h0*8 + n] : 0.f;
    float hi = (n<8) ? src[(h0+1)*8 + n] : 0.f;
    wsU[W2F1 + i] = pkh2(lo, hi);
    return;
  }
  i -= 7680;
  if (i < 256){
    int u = i>>4, n = i&15;
    const float* src = (u<9) ? S.p[3]+u*8 : (u<12) ? S.p[7]+(u-9)*8
                     : (u<15) ? S.p[11]+(u-12)*8 : S.p[16];
    wsF[OFF_b2P0 + i] = (n<8) ? src[n] : 0.f;
    return;
  }
  i -= 256;
  if (i < 240){
    int u = i>>4, n = i&15;
    const float* src = (u<9) ? S.p[21]+u*8 : (u<12) ? S.p[25]+(u-9)*8
                               : S.p[29]+(u-12)*8;
    wsF[OFF_b2P1 + i] = (n<8) ? src[n] : 0.f;
    return;
  }
  i -= 240;
  if (i < 72){   // G0W3H packed: [3t][6m][4jp], pair jp = cols j=2jp,2jp+1
    int t = i/24, m = (i>>2)%6, jp = i&3;
    const float* src = S.p[12] + t*48;
    wsU[OFF_G0W3 + i] = pkh2(src[(2*jp)*6 + m], src[(2*jp+1)*6 + m]);
    return;
  }
  i -= 72;
  if (i < 48){   // SG0W3H packed: [12m][4jp]
    int m = i>>2, jp = i&3;
    const float* src = S.p[17];
    wsU[OFF_SG0W3 + i] = pkh2(src[(2*jp)*12 + m], src[(2*jp+1)*12 + m]);
    return;
  }
  i -= 48;
  if (i < 72){   // G1W3H packed: [3t][6m][4jp]
    int t = i/24, m = (i>>2)%6, jp = i&3;
    const float* src = S.p[30] + t*48;
    wsU[OFF_G1W3 + i] = pkh2(src[(2*jp)*6 + m], src[(2*jp+1)*6 + m]);
    return;
  }
  i -= 72;
  if (i < 3){ wsF[OFF_Tb + i] = S.p[32][i]; return; }
  i -= 3;
  { // TWH: [t][w] = pkh2(TW[t][2w], TW[t][2w+1])
    int t = i>>2, w = i&3;
    wsU[OFF_TWH + i] = pkh2(S.p[31][t*8 + 2*w], S.p[31][t*8 + 2*w + 1]);
  }
}

template<int N>
__device__ __forceinline__ void softmaxT(float (&v)[N]){
  float m = v[0];
  #pragma unroll
  for (int i=1;i<N;i++) m = fmaxf(m, v[i]);
  float s = 0.f;
  #pragma unroll
  for (int i=0;i<N;i++){ v[i] = __expf(v[i]-m); s += v[i]; }
  float inv = 1.f/s;
  #pragma unroll
  for (int i=0;i<N;i++) v[i] *= inv;
}

__global__ __launch_bounds__(NT, 4) void ple_kernel(
    const float* __restrict__ emb, const int* __restrict__ cat,
    const u32* __restrict__ wsU, const float* __restrict__ P,
    float* __restrict__ out, int Btot)
{
  // LDS (u32): xsA [128e][36] aliased as l1in; obT u-major
  // [16u][128e][4w]; ONES/ZERO 4-slot const at end. 51.2KB -> 3 blk/CU.
  __shared__ u32 S_[12804];
  u32* xsA = S_;            // 4608
  u32* obT = S_ + 4608;     // 8192
  u32* ONESp = S_ + 12800;  // {0x3C00,0,0,0}: q2 -> {1h,0,0,0}, q3 -> zeros
  const int tid = threadIdx.x;
  const int e = tid & (EPB-1);     // element (phases 0,2,4)
  const int w = tid >> 7;          // worker 0..3 (phases 0,2,4)
  const int su = __builtin_amdgcn_readfirstlane(tid >> 6); // wave 0..7
  const int lane = tid & 63;
  const int q = lane >> 4;
  const int c16 = lane & 15;
  const half8 z8 = (half8){(__fp16)0,(__fp16)0,(__fp16)0,(__fp16)0,
                           (__fp16)0,(__fp16)0,(__fp16)0,(__fp16)0};

  // ---- phase 0: gather x -> xsA [e][36] f16 pairs ----
  {
    const int eg = blockIdx.x*EPB + e;
    auto ldf = [&](int f){
      int idx = cat[eg*9 + f];
      const float* ep = emb + (long)idx*8;
      float4 a = *(const float4*)ep;
      float4 b = *(const float4*)(ep+4);
      uint4 pk4; pk4.x = pkh2(a.x,a.y); pk4.y = pkh2(a.z,a.w);
      pk4.z = pkh2(b.x,b.y); pk4.w = pkh2(b.z,b.w);
      *(uint4*)(xsA + e*XST + f*4) = pk4;
    };
    ldf(w); ldf(w+4);
    if (w == (e>>5)) ldf(8);   // spread field-8 across workers
    if (tid == 0)
      *(uint4*)ONESp = (uint4){0x00003C00u, 0u, 0u, 0u};
  }
  __syncthreads();

  // ---- phase 1: level-0; s=0,1 K32 + s=2 K16 (bias in k=72 row) ----
  {
    #pragma unroll
    for (int k2 = 0; k2 < 2; k2++){
      const int u = su*2 + k2;
      half8 bf[2][4];
      #pragma unroll
      for (int s=0;s<2;s++)
        #pragma unroll
        for (int t=0;t<4;t++)
          bf[s][t] = *(const half8*)(wsU + W1F0 + (((u*2+s)*4+t)*64 + lane)*4);
      // s=2 compact K16 frags: layout already holds bias row + zeros.
      half4 bfc[4];
      #pragma unroll
      for (int t=0;t<4;t++)
        bfc[t] = *(const half4*)(wsU + W1F0C + ((u*4+t)*64 + lane)*2);
      float4 b2v = *(const float4*)(P + OFF_b2P0 + u*16 + q*4);
      // W2: rows n>=8 are zero -> read n&7 slot, select 0 (1/2 traffic).
      half8 w2f[2];
      #pragma unroll
      for (int ks=0;ks<2;ks++){
        half8 raw = *(const half8*)(wsU + W2F0 + ((u*2+ks)*64 + q*16 + (c16&7))*4);
        w2f[ks] = (c16 < 8) ? raw : z8;
      }

      #pragma unroll 2
      for (int m=0;m<8;m++){
        half8 af0 = *(const half8*)(xsA + (m*16 + c16)*XST + q*4);
        half8 af1 = *(const half8*)(xsA + (m*16 + c16)*XST + 16 + q*4);
        // K16 B-frag: q0 -> x[64..67], q1 -> x[68..71], q2 -> {1,0,0,0}
        // (activates k=72 bias row), q3 -> zeros.
        const u32* a2p = (q < 2) ? (xsA + (m*16 + c16)*XST + 32 + 2*q)
                                 : (ONESp + (q-2)*2);
        half4 af2 = *(const half4*)a2p;
        floatx4 acc[4];
        #pragma unroll
        for (int t=0;t<4;t++) acc[t] = (floatx4){0.f,0.f,0.f,0.f};
        #pragma unroll
        for (int t=0;t<4;t++)
          acc[t] = __builtin_amdgcn_mfma_f32_16x16x32_f16(bf[0][t], af0, acc[t], 0,0,0);
        #pragma unroll
        for (int t=0;t<4;t++)
          acc[t] = __builtin_amdgcn_mfma_f32_16x16x32_f16(bf[1][t], af1, acc[t], 0,0,0);
        #pragma unroll
        for (int t=0;t<4;t++)
          acc[t] = __builtin_amdgcn_mfma_f32_16x16x16f16(bfc[t], af2, acc[t], 0,0,0);
        // lane holds H[e=c16][h=t*16+q*4+r]; pack + f16-relu to W2-B frags
        floatx4 oc = (floatx4){b2v.x, b2v.y, b2v.z, b2v.w};
        #pragma unroll
        for (int ks=0;ks<2;ks++){
          u32 aw[4];
          aw[0] = pkrelu(acc[2*ks  ][0], acc[2*ks  ][1]);
          aw[1] = pkrelu(acc[2*ks  ][2], acc[2*ks  ][3]);
          aw[2] = pkrelu(acc[2*ks+1][0], acc[2*ks+1][1]);
          aw[3] = pkrelu(acc[2*ks+1][2], acc[2*ks+1][3]);
          half8 haf; __builtin_memcpy(&haf, aw, 16);
          oc = __builtin_amdgcn_mfma_f32_16x16x32_f16(w2f[ks], haf, oc, 0,0,0);
        }
        // lane holds O[e=c16][n=q*4+r]; q<2 covers n=0..7 -> one b64 store
        if (q < 2){
          uint2 ov;
          ov.x = pkrelu(oc[0], oc[1]);
          ov.y = pkrelu(oc[2], oc[3]);
          *(uint2*)(obT + u*512 + (m*16 + c16)*4 + q*2) = ov;
        }
      }
    }
  }

  // ---- cross-barrier prefetch: phase-3 W1F1C frags (wsU is constant,
  // so these loads are legal before the barrier; the compiler cannot
  // hoist them past the fence itself). Carried in regs through phase 2.
  half4 pf1c[2][4];
  {
    #pragma unroll
    for (int k2=0;k2<2;k2++){
      const int uu = su*2 + k2;
      const int uc = (uu < 15) ? uu : 14;   // wave7/k2=1 unused, keep in-bounds
      #pragma unroll
      for (int t=0;t<4;t++)
        pf1c[k2][t] = *(const half4*)(wsU + W1F1C + ((uc*4+t)*64 + lane)*2);
    }
  }
  __syncthreads();

  // ---- phase 2: level-0 gates (dot2) + sparse pk_fma mixing -> l1in ----
  u32* l1in = xsA;
  {
    hv2 a01 = (hv2){0,0}, a23 = (hv2){0,0}, a45 = (hv2){0,0}, a67 = (hv2){0,0};
    int dst;
    if (w < 3){
      uint4 gw = *(const uint4*)(obT + (12+w)*512 + e*4);
      float lg[6];
      #pragma unroll
      for (int m=0;m<6;m++){
        const int o = OFF_G0W3 + (w*6+m)*4;
        float s = dot2(gw.x, wsU[o+0], 0.f);
        s = dot2(gw.y, wsU[o+1], s);
        s = dot2(gw.z, wsU[o+2], s);
        s = dot2(gw.w, wsU[o+3], s);
        lg[m] = s;
      }
      softmaxT<6>(lg);
      // only units {3w..3w+2} (w/ lg[0..2]) and {9..11} (w/ lg[3..5]) mix
      #pragma unroll
      for (int i=0;i<6;i++){
        const int u = (i<3) ? (3*w + i) : (6 + i);
        uint4 ow = *(const uint4*)(obT + u*512 + e*4);
        __fp16 wh = (__fp16)lg[i];
        hv2 wp = (hv2){wh, wh};
        a01 = u2h(ow.x)*wp + a01;
        a23 = u2h(ow.y)*wp + a23;
        a45 = u2h(ow.z)*wp + a45;
        a67 = u2h(ow.w)*wp + a67;
      }
      dst = w*4;
    } else {
      uint4 gw = *(const uint4*)(obT + 15*512 + e*4);
      float lw[12];
      #pragma unroll
      for (int m=0;m<12;m++){
        const int o = OFF_SG0W3 + m*4;
        float s = dot2(gw.x, wsU[o+0], 0.f);
        s = dot2(gw.y, wsU[o+1], s);
        s = dot2(gw.z, wsU[o+2], s);
        s = dot2(gw.w, wsU[o+3], s);
        lw[m] = s;
      }
      softmaxT<12>(lw);
      #pragma unroll
      for (int u=0;u<12;u++){
        uint4 ow = *(const uint4*)(obT + u*512 + e*4);
        __fp16 wh = (__fp16)lw[u];
        hv2 wp = (hv2){wh, wh};
        a01 = u2h(ow.x)*wp + a01;
        a23 = u2h(ow.y)*wp + a23;
        a45 = u2h(ow.z)*wp + a45;
        a67 = u2h(ow.w)*wp + a67;
      }
      dst = 12;
    }
    uint4 lw4; lw4.x = h2u(a01); lw4.y = h2u(a23);
    lw4.z = h2u(a45); lw4.w = h2u(a67);
    *(uint4*)(l1in + e*XST + dst) = lw4;
  }
  __syncthreads();

  // ---- phase 3: level-1, K16 GEMM1 (prefetched frags) + K32 GEMM2 ----
  {
    #pragma unroll
    for (int k2=0;k2<2;k2++){
      const int u = su*2 + k2;
      if (u >= 15) break;
      const int base_u = (u<9) ? (u/3)*4 : ((u<12) ? 12 : (u-12)*4);
      float4 b2v = *(const float4*)(P + OFF_b2P1 + u*16 + q*4);
      half8 w2f[2];
      #pragma unroll
      for (int ks=0;ks<2;ks++){
        half8 raw = *(const half8*)(wsU + W2F1 + ((u*2+ks)*64 + q*16 + (c16&7))*4);
        w2f[ks] = (c16 < 8) ? raw : z8;
      }

      #pragma unroll 2
      for (int m=0;m<8;m++){
        // K16 B-frag: q0 -> in[0..3], q1 -> in[4..7], q2 -> {1,0,0,0}
        // (activates k=8 bias row), q3 -> zeros.
        const u32* ap = (q < 2) ? (l1in + (m*16 + c16)*XST + base_u + 2*q)
                                : (ONESp + (q-2)*2);
        half4 af = *(const half4*)ap;
        floatx4 acc[4];
        #pragma unroll
        for (int t=0;t<4;t++) acc[t] = (floatx4){0.f,0.f,0.f,0.f};
        #pragma unroll
        for (int t=0;t<4;t++)
          acc[t] = __builtin_amdgcn_mfma_f32_16x16x16f16(pf1c[k2][t], af, acc[t], 0,0,0);
        floatx4 oc = (floatx4){b2v.x, b2v.y, b2v.z, b2v.w};
        #pragma unroll
        for (int ks=0;ks<2;ks++){
          u32 aw[4];
          aw[0] = pkrelu(acc[2*ks  ][0], acc[2*ks  ][1]);
          aw[1] = pkrelu(acc[2*ks  ][2], acc[2*ks  ][3]);
          aw[2] = pkrelu(acc[2*ks+1][0], acc[2*ks+1][1]);
          aw[3] = pkrelu(acc[2*ks+1][2], acc[2*ks+1][3]);
          half8 haf; __builtin_memcpy(&haf, aw, 16);
          oc = __builtin_amdgcn_mfma_f32_16x16x32_f16(w2f[ks], haf, oc, 0,0,0);
        }
        if (q < 2){
          uint2 ov;
          ov.x = pkrelu(oc[0], oc[1]);
          ov.y = pkrelu(oc[2], oc[3]);
          *(uint2*)(obT + u*512 + (m*16 + c16)*4 + q*2) = ov;
        }
      }
    }
  }
  __syncthreads();

  // ---- phase 4: level-1 gates (dot2) + sparse mixing + towers ----
  if (w < 3){
    const int t = w;
    uint4 gw = *(const uint4*)(obT + (12+t)*512 + e*4);
    float lg[6];
    #pragma unroll
    for (int m=0;m<6;m++){
      const int o = OFF_G1W3 + (t*6+m)*4;
      float s = dot2(gw.x, wsU[o+0], 0.f);
      s = dot2(gw.y, wsU[o+1], s);
      s = dot2(gw.z, wsU[o+2], s);
      s = dot2(gw.w, wsU[o+3], s);
      lg[m] = s;
    }
    softmaxT<6>(lg);
    hv2 a01 = (hv2){0,0}, a23 = (hv2){0,0}, a45 = (hv2){0,0}, a67 = (hv2){0,0};
    #pragma unroll
    for (int i=0;i<6;i++){
      const int u = (i<3) ? (3*t + i) : (6 + i);
      uint4 ow = *(const uint4*)(obT + u*512 + e*4);
      __fp16 wh = (__fp16)lg[i];
      hv2 wp = (hv2){wh, wh};
      a01 = u2h(ow.x)*wp + a01;
      a23 = u2h(ow.y)*wp + a23;
      a45 = u2h(ow.z)*wp + a45;
      a67 = u2h(ow.w)*wp + a67;
    }
    float s = P[OFF_Tb + t];
    s = dot2(h2u(a01), wsU[OFF_TWH + t*4 + 0], s);
    s = dot2(h2u(a23), wsU[OFF_TWH + t*4 + 1], s);
    s = dot2(h2u(a45), wsU[OFF_TWH + t*4 + 2], s);
    s = dot2(h2u(a67), wsU[OFF_TWH + t*4 + 3], s);
    out[t*Btot + blockIdx.x*EPB + e] = 1.f/(1.f + __expf(-s));
  }
}

extern "C" void kernel_launch(void* const* d_in, const int* in_sizes, int n_in,
                              void* d_out, int out_size, void* d_ws, size_t ws_size,
                              hipStream_t stream)
{
  const float* emb = (const float*)d_in[0];
  const int* cat = (const int*)d_in[34];
  float* out = (float*)d_out;
  u32* wsU = (u32*)d_ws;
  float* wsF = (float*)d_ws;
  PSrc S;
  for (int k=0;k<33;k++) S.p[k] = (const float*)d_in[k+1];
  const int B = in_sizes[34] / 9;   // 131072

  cvt_kernel<<<(CVT_TOTAL+255)/256, 256, 0, stream>>>(S, wsU, wsF);
  ple_kernel<<<B/EPB, NT, 0, stream>>>(emb, cat, wsU, wsF, out, B);
}

// Round 11
// 164.679 us; speedup vs baseline: 1.0237x; 1.0237x over previous
//
#include <hip/hip_runtime.h>

// PLELayer round-28: extend r27's validated cross-barrier prefetch to
// ALL phase heads. r27 post-mortem: prefetch = real (+0.5-1us/head),
// VGPR 52 w/ headroom to 80 (6 waves/SIMD, LDS-bound 3 blk/CU).
// 1) Phase-1 u0 frags (bf 16 + bfc 8 + w2f 8 = 32 VGPR) issued BEFORE
//    the phase-0 gather: L2 weight loads (~200cyc) hide under the
//    gather's HBM latency (~600-900cyc); phase 1 opens compute-ready.
// 2) Phase-3 W2F1 frags (pw2f 16 VGPR) prefetched next to pf1c before
//    the phase-2 barrier.
// Tripwires: VGPR>80 (residency loss), WRITE>1536 (spill).
// Predict dur 46.5-48.5; flat => phase heads covered, structural
// plateau (all pipes <40%, latency-bound).

#define NT 512
#define EPB 128
#define XST 36   // xsA/l1in stride in u32 (mult of 4 -> aligned; s4=9 odd)

typedef unsigned short u16;
typedef unsigned int u32;
typedef __fp16 hv2 __attribute__((ext_vector_type(2)));
typedef __fp16 half4 __attribute__((ext_vector_type(4)));
typedef __fp16 half8 __attribute__((ext_vector_type(8)));
typedef __attribute__((ext_vector_type(4))) float floatx4;

__device__ __forceinline__ u32 pkh2(float a, float b){
  hv2 v = __builtin_amdgcn_cvt_pkrtz(a, b);
  u32 r; __builtin_memcpy(&r, &v, 4); return r;
}
__device__ __forceinline__ hv2 u2h(u32 w){ hv2 v; __builtin_memcpy(&v, &w, 4); return v; }
__device__ __forceinline__ u32 h2u(hv2 v){ u32 w; __builtin_memcpy(&w, &v, 4); return w; }
__device__ __forceinline__ float dot2(u32 a, u32 b, float c){
  return __builtin_amdgcn_fdot2(u2h(a), u2h(b), c, false);
}
// pack two f32 then relu in f16 (v_cvt_pkrtz + v_pk_max_f16)
__device__ __forceinline__ u32 pkrelu(float a, float b){
  hv2 v = __builtin_amdgcn_cvt_pkrtz(a, b);
  hv2 z = (hv2){(__fp16)0.f, (__fp16)0.f};
  return h2u(__builtin_elementwise_max(v, z));
}

// ---- ws layout (u32 offsets) ----
#define W1F0 0          // [16u][2s][4t][64l][4] = 32768 (s=0,1 K32 frags)
#define W1F0C 32768     // [16u][4t][64l][2]     =  8192 (s=2 K16: k=64+q*4+2j2(+b); k72=b1; 0-pad)
#define W2F0 40960      // [16u][2ks][64l][4]    =  8192 (h'(q,ks,j) perm)
#define W1F1C 49152     // [15u][4t][64l][2]     =  7680 (K16: k=q*4+2j2(+b); k8=b1; 0-pad)
#define W2F1 56832      // [15u][2ks][64l][4]    =  7680 (h' perm)
#define OFF_b2P0 64512  // [16][16] cols 8..15 zero
#define OFF_b2P1 64768  // [15][16] cols 8..15 zero
#define OFF_G0W3 65008  // [3t][6m][4jp] packed f16 pairs = 72
#define OFF_SG0W3 65080 // [12m][4jp] = 48
#define OFF_G1W3 65128  // [3t][6m][4jp] = 72
#define OFF_Tb 65200    // [3]
#define OFF_TWH 65203   // [3][4] u32: packed f16 pairs of tower_W
#define CVT_TOTAL 65215

struct PSrc { const float* p[33]; };

__global__ void cvt_kernel(PSrc S, u32* __restrict__ wsU, float* __restrict__ wsF){
  int i = blockIdx.x*256 + threadIdx.x;
  if (i >= CVT_TOTAL) return;
  if (i < 32768){  // W1F0 s=0,1: lane holds W1[k=s*32+q*8+2j2(+b)][h=t*16+c16]
    int j2 = i & 3, l = (i>>2)&63, tt = (i>>8)&3;
    int rest = i >> 10; int s = rest & 1, u = rest >> 1;
    int k0 = s*32 + (l>>4)*8 + 2*j2;
    int h  = tt*16 + (l&15);
    const float* src = (u<9)  ? S.p[0]  + (u*72)*64
                     : (u<12) ? S.p[4]  + ((u-9)*72)*64
                     : (u<15) ? S.p[8]  + ((u-12)*72)*64
                              : S.p[13];
    wsU[i] = pkh2(src[k0*64 + h], src[(k0+1)*64 + h]);   // k0+1 <= 63 < 72
    return;
  }
  i -= 32768;
  if (i < 8192){   // W1F0C (s=2, K16): k0 = 64 + q*4 + 2*j2; k72 = bias; >72 -> 0
    int j2 = i & 1, l = (i>>1)&63, tt = (i>>7)&3, u = i>>9;
    int k0 = 64 + (l>>4)*4 + 2*j2;
    int h  = tt*16 + (l&15);
    const float* src = (u<9)  ? S.p[0]  + (u*72)*64
                     : (u<12) ? S.p[4]  + ((u-9)*72)*64
                     : (u<15) ? S.p[8]  + ((u-12)*72)*64
                              : S.p[13];
    const float* bsrc = (u<9)  ? S.p[1] + u*64
                      : (u<12) ? S.p[5] + (u-9)*64
                      : (u<15) ? S.p[9] + (u-12)*64
                               : S.p[14];
    float lo = (k0 < 72) ? src[k0*64 + h] : ((k0==72) ? bsrc[h] : 0.f);
    float hi = (k0+1 < 72) ? src[(k0+1)*64 + h] : 0.f;
    wsU[W1F0C + i] = pkh2(lo, hi);
    return;
  }
  i -= 8192;
  if (i < 8192){   // W2F0: W2[h'(q,ks,j)][n=l&15], n>=8 -> 0
    int j2 = i & 3, l = (i>>2)&63, ks = (i>>8)&1, u = i>>9;
    int q = l >> 4, n = l & 15;
    int h0 = (2*ks + ((2*j2)>>2))*16 + q*4 + ((2*j2)&3);
    const float* src = (u<9)  ? S.p[2]  + u*512
                     : (u<12) ? S.p[6]  + (u-9)*512
                     : (u<15) ? S.p[10] + (u-12)*512
                              : S.p[15];
    float lo = (n<8) ? src[h0*8 + n] : 0.f;
    float hi = (n<8) ? src[(h0+1)*8 + n] : 0.f;
    wsU[W2F0 + i] = pkh2(lo, hi);
    return;
  }
  i -= 8192;
  if (i < 7680){   // W1F1C (K16): k0 = q*4 + 2*j2; k8 = bias; >8 -> 0
    int j2 = i & 1, l = (i>>1)&63, tt = (i>>7)&3, u = i>>9;
    int k0 = (l>>4)*4 + 2*j2;
    int n = tt*16 + (l&15);
    const float* src = (u<9) ? S.p[18] + (u*8)*64
                     : (u<12) ? S.p[22] + ((u-9)*8)*64
                              : S.p[26] + ((u-12)*8)*64;
    const float* bsrc = (u<9) ? S.p[19] + u*64
                      : (u<12) ? S.p[23] + (u-9)*64
                               : S.p[27] + (u-12)*64;
    float lo = (k0 < 8) ? src[k0*64 + n] : ((k0==8) ? bsrc[n] : 0.f);
    float hi = (k0+1 < 8) ? src[(k0+1)*64 + n] : 0.f;
    wsU[W1F1C + i] = pkh2(lo, hi);
    return;
  }
  i -= 7680;
  if (i < 7680){   // W2F1: h'(q,ks,j) permutation, n>=8 -> 0
    int j2 = i & 3, l = (i>>2)&63, ks = (i>>8)&1, u = i>>9;
    int q = l >> 4, n = l & 15;
    int h0 = (2*ks + ((2*j2)>>2))*16 + q*4 + ((2*j2)&3);
    const float* src = (u<9) ? S.p[20] + u*512
                     : (u<12) ? S.p[24] + (u-9)*512
                              : S.p[28] + (u-12)*512;
    float lo = (n<8) ? src[h0*8 + n] : 0.f;
    float hi = (n<8) ? src[(h0+1)*8 + n] : 0.f;
    wsU[W2F1 + i] = pkh2(lo, hi);
    return;
  }
  i -= 7680;
  if (i < 256){
    int u = i>>4, n = i&15;
    const float* src = (u<9) ? S.p[3]+u*8 : (u<12) ? S.p[7]+(u-9)*8
                     : (u<15) ? S.p[11]+(u-12)*8 : S.p[16];
    wsF[OFF_b2P0 + i] = (n<8) ? src[n] : 0.f;
    return;
  }
  i -= 256;
  if (i < 240){
    int u = i>>4, n = i&15;
    const float* src = (u<9) ? S.p[21]+u*8 : (u<12) ? S.p[25]+(u-9)*8
                               : S.p[29]+(u-12)*8;
    wsF[OFF_b2P1 + i] = (n<8) ? src[n] : 0.f;
    return;
  }
  i -= 240;
  if (i < 72){   // G0W3H packed: [3t][6m][4jp], pair jp = cols j=2jp,2jp+1
    int t = i/24, m = (i>>2)%6, jp = i&3;
    const float* src = S.p[12] + t*48;
    wsU[OFF_G0W3 + i] = pkh2(src[(2*jp)*6 + m], src[(2*jp+1)*6 + m]);
    return;
  }
  i -= 72;
  if (i < 48){   // SG0W3H packed: [12m][4jp]
    int m = i>>2, jp = i&3;
    const float* src = S.p[17];
    wsU[OFF_SG0W3 + i] = pkh2(src[(2*jp)*12 + m], src[(2*jp+1)*12 + m]);
    return;
  }
  i -= 48;
  if (i < 72){   // G1W3H packed: [3t][6m][4jp]
    int t = i/24, m = (i>>2)%6, jp = i&3;
    const float* src = S.p[30] + t*48;
    wsU[OFF_G1W3 + i] = pkh2(src[(2*jp)*6 + m], src[(2*jp+1)*6 + m]);
    return;
  }
  i -= 72;
  if (i < 3){ wsF[OFF_Tb + i] = S.p[32][i]; return; }
  i -= 3;
  { // TWH: [t][w] = pkh2(TW[t][2w], TW[t][2w+1])
    int t = i>>2, w = i&3;
    wsU[OFF_TWH + i] = pkh2(S.p[31][t*8 + 2*w], S.p[31][t*8 + 2*w + 1]);
  }
}

template<int N>
__device__ __forceinline__ void softmaxT(float (&v)[N]){
  float m = v[0];
  #pragma unroll
  for (int i=1;i<N;i++) m = fmaxf(m, v[i]);
  float s = 0.f;
  #pragma unroll
  for (int i=0;i<N;i++){ v[i] = __expf(v[i]-m); s += v[i]; }
  float inv = 1.f/s;
  #pragma unroll
  for (int i=0;i<N;i++) v[i] *= inv;
}

__global__ __launch_bounds__(NT, 4) void ple_kernel(
    const float* __restrict__ emb, const int* __restrict__ cat,
    const u32* __restrict__ wsU, const float* __restrict__ P,
    float* __restrict__ out, int Btot)
{
  // LDS (u32): xsA [128e][36] aliased as l1in; obT u-major
  // [16u][128e][4w]; ONES/ZERO 4-slot const at end. 51.2KB -> 3 blk/CU.
  __shared__ u32 S_[12804];
  u32* xsA = S_;            // 4608
  u32* obT = S_ + 4608;     // 8192
  u32* ONESp = S_ + 12800;  // {0x3C00,0,0,0}: q2 -> {1h,0,0,0}, q3 -> zeros
  const int tid = threadIdx.x;
  const int e = tid & (EPB-1);     // element (phases 0,2,4)
  const int w = tid >> 7;          // worker 0..3 (phases 0,2,4)
  const int su = __builtin_amdgcn_readfirstlane(tid >> 6); // wave 0..7
  const int lane = tid & 63;
  const int q = lane >> 4;
  const int c16 = lane & 15;
  const half8 z8 = (half8){(__fp16)0,(__fp16)0,(__fp16)0,(__fp16)0,
                           (__fp16)0,(__fp16)0,(__fp16)0,(__fp16)0};

  // ---- prefetch phase-1 unit-0 weight frags (L2) BEFORE the gather:
  // they complete under the gather's HBM latency. wsU is constant.
  half8 p1bf[2][4];
  half4 p1bfc[4];
  half8 p1w2f[2];
  {
    const int u0 = su*2;
    #pragma unroll
    for (int s=0;s<2;s++)
      #pragma unroll
      for (int t=0;t<4;t++)
        p1bf[s][t] = *(const half8*)(wsU + W1F0 + (((u0*2+s)*4+t)*64 + lane)*4);
    #pragma unroll
    for (int t=0;t<4;t++)
      p1bfc[t] = *(const half4*)(wsU + W1F0C + ((u0*4+t)*64 + lane)*2);
    #pragma unroll
    for (int ks=0;ks<2;ks++){
      half8 raw = *(const half8*)(wsU + W2F0 + ((u0*2+ks)*64 + q*16 + (c16&7))*4);
      p1w2f[ks] = (c16 < 8) ? raw : z8;
    }
  }

  // ---- phase 0: gather x -> xsA [e][36] f16 pairs ----
  {
    const int eg = blockIdx.x*EPB + e;
    auto ldf = [&](int f){
      int idx = cat[eg*9 + f];
      const float* ep = emb + (long)idx*8;
      float4 a = *(const float4*)ep;
      float4 b = *(const float4*)(ep+4);
      uint4 pk4; pk4.x = pkh2(a.x,a.y); pk4.y = pkh2(a.z,a.w);
      pk4.z = pkh2(b.x,b.y); pk4.w = pkh2(b.z,b.w);
      *(uint4*)(xsA + e*XST + f*4) = pk4;
    };
    ldf(w); ldf(w+4);
    if (w == (e>>5)) ldf(8);   // spread field-8 across workers
    if (tid == 0)
      *(uint4*)ONESp = (uint4){0x00003C00u, 0u, 0u, 0u};
  }
  __syncthreads();

  // ---- phase 1: level-0; s=0,1 K32 + s=2 K16 (bias in k=72 row) ----
  {
    #pragma unroll
    for (int k2 = 0; k2 < 2; k2++){
      const int u = su*2 + k2;
      half8 bf[2][4];
      half4 bfc[4];
      half8 w2f[2];
      if (k2 == 0){
        #pragma unroll
        for (int s=0;s<2;s++)
          #pragma unroll
          for (int t=0;t<4;t++) bf[s][t] = p1bf[s][t];
        #pragma unroll
        for (int t=0;t<4;t++) bfc[t] = p1bfc[t];
        #pragma unroll
        for (int ks=0;ks<2;ks++) w2f[ks] = p1w2f[ks];
      } else {
        #pragma unroll
        for (int s=0;s<2;s++)
          #pragma unroll
          for (int t=0;t<4;t++)
            bf[s][t] = *(const half8*)(wsU + W1F0 + (((u*2+s)*4+t)*64 + lane)*4);
        #pragma unroll
        for (int t=0;t<4;t++)
          bfc[t] = *(const half4*)(wsU + W1F0C + ((u*4+t)*64 + lane)*2);
        #pragma unroll
        for (int ks=0;ks<2;ks++){
          half8 raw = *(const half8*)(wsU + W2F0 + ((u*2+ks)*64 + q*16 + (c16&7))*4);
          w2f[ks] = (c16 < 8) ? raw : z8;
        }
      }
      float4 b2v = *(const float4*)(P + OFF_b2P0 + u*16 + q*4);

      #pragma unroll 2
      for (int m=0;m<8;m++){
        half8 af0 = *(const half8*)(xsA + (m*16 + c16)*XST + q*4);
        half8 af1 = *(const half8*)(xsA + (m*16 + c16)*XST + 16 + q*4);
        // K16 B-frag: q0 -> x[64..67], q1 -> x[68..71], q2 -> {1,0,0,0}
        // (activates k=72 bias row), q3 -> zeros.
        const u32* a2p = (q < 2) ? (xsA + (m*16 + c16)*XST + 32 + 2*q)
                                 : (ONESp + (q-2)*2);
        half4 af2 = *(const half4*)a2p;
        floatx4 acc[4];
        #pragma unroll
        for (int t=0;t<4;t++) acc[t] = (floatx4){0.f,0.f,0.f,0.f};
        #pragma unroll
        for (int t=0;t<4;t++)
          acc[t] = __builtin_amdgcn_mfma_f32_16x16x32_f16(bf[0][t], af0, acc[t], 0,0,0);
        #pragma unroll
        for (int t=0;t<4;t++)
          acc[t] = __builtin_amdgcn_mfma_f32_16x16x32_f16(bf[1][t], af1, acc[t], 0,0,0);
        #pragma unroll
        for (int t=0;t<4;t++)
          acc[t] = __builtin_amdgcn_mfma_f32_16x16x16f16(bfc[t], af2, acc[t], 0,0,0);
        // lane holds H[e=c16][h=t*16+q*4+r]; pack + f16-relu to W2-B frags
        floatx4 oc = (floatx4){b2v.x, b2v.y, b2v.z, b2v.w};
        #pragma unroll
        for (int ks=0;ks<2;ks++){
          u32 aw[4];
          aw[0] = pkrelu(acc[2*ks  ][0], acc[2*ks  ][1]);
          aw[1] = pkrelu(acc[2*ks  ][2], acc[2*ks  ][3]);
          aw[2] = pkrelu(acc[2*ks+1][0], acc[2*ks+1][1]);
          aw[3] = pkrelu(acc[2*ks+1][2], acc[2*ks+1][3]);
          half8 haf; __builtin_memcpy(&haf, aw, 16);
          oc = __builtin_amdgcn_mfma_f32_16x16x32_f16(w2f[ks], haf, oc, 0,0,0);
        }
        // lane holds O[e=c16][n=q*4+r]; q<2 covers n=0..7 -> one b64 store
        if (q < 2){
          uint2 ov;
          ov.x = pkrelu(oc[0], oc[1]);
          ov.y = pkrelu(oc[2], oc[3]);
          *(uint2*)(obT + u*512 + (m*16 + c16)*4 + q*2) = ov;
        }
      }
    }
  }

  // ---- cross-barrier prefetch for phase 3: W1F1C + W2F1 frags.
  // wsU is constant; loads are legal before the barrier and hide the
  // phase-3 head latency under phase 2's gate computation.
  half4 pf1c[2][4];
  half8 pw2f[2][2];
  {
    #pragma unroll
    for (int k2=0;k2<2;k2++){
      const int uu = su*2 + k2;
      const int uc = (uu < 15) ? uu : 14;   // wave7/k2=1 unused, keep in-bounds
      #pragma unroll
      for (int t=0;t<4;t++)
        pf1c[k2][t] = *(const half4*)(wsU + W1F1C + ((uc*4+t)*64 + lane)*2);
      #pragma unroll
      for (int ks=0;ks<2;ks++){
        half8 raw = *(const half8*)(wsU + W2F1 + ((uc*2+ks)*64 + q*16 + (c16&7))*4);
        pw2f[k2][ks] = (c16 < 8) ? raw : z8;
      }
    }
  }
  __syncthreads();

  // ---- phase 2: level-0 gates (dot2) + sparse pk_fma mixing -> l1in ----
  u32* l1in = xsA;
  {
    hv2 a01 = (hv2){0,0}, a23 = (hv2){0,0}, a45 = (hv2){0,0}, a67 = (hv2){0,0};
    int dst;
    if (w < 3){
      uint4 gw = *(const uint4*)(obT + (12+w)*512 + e*4);
      float lg[6];
      #pragma unroll
      for (int m=0;m<6;m++){
        const int o = OFF_G0W3 + (w*6+m)*4;
        float s = dot2(gw.x, wsU[o+0], 0.f);
        s = dot2(gw.y, wsU[o+1], s);
        s = dot2(gw.z, wsU[o+2], s);
        s = dot2(gw.w, wsU[o+3], s);
        lg[m] = s;
      }
      softmaxT<6>(lg);
      // only units {3w..3w+2} (w/ lg[0..2]) and {9..11} (w/ lg[3..5]) mix
      #pragma unroll
      for (int i=0;i<6;i++){
        const int u = (i<3) ? (3*w + i) : (6 + i);
        uint4 ow = *(const uint4*)(obT + u*512 + e*4);
        __fp16 wh = (__fp16)lg[i];
        hv2 wp = (hv2){wh, wh};
        a01 = u2h(ow.x)*wp + a01;
        a23 = u2h(ow.y)*wp + a23;
        a45 = u2h(ow.z)*wp + a45;
        a67 = u2h(ow.w)*wp + a67;
      }
      dst = w*4;
    } else {
      uint4 gw = *(const uint4*)(obT + 15*512 + e*4);
      float lw[12];
      #pragma unroll
      for (int m=0;m<12;m++){
        const int o = OFF_SG0W3 + m*4;
        float s = dot2(gw.x, wsU[o+0], 0.f);
        s = dot2(gw.y, wsU[o+1], s);
        s = dot2(gw.z, wsU[o+2], s);
        s = dot2(gw.w, wsU[o+3], s);
        lw[m] = s;
      }
      softmaxT<12>(lw);
      #pragma unroll
      for (int u=0;u<12;u++){
        uint4 ow = *(const uint4*)(obT + u*512 + e*4);
        __fp16 wh = (__fp16)lw[u];
        hv2 wp = (hv2){wh, wh};
        a01 = u2h(ow.x)*wp + a01;
        a23 = u2h(ow.y)*wp + a23;
        a45 = u2h(ow.z)*wp + a45;
        a67 = u2h(ow.w)*wp + a67;
      }
      dst = 12;
    }
    uint4 lw4; lw4.x = h2u(a01); lw4.y = h2u(a23);
    lw4.z = h2u(a45); lw4.w = h2u(a67);
    *(uint4*)(l1in + e*XST + dst) = lw4;
  }
  __syncthreads();

  // ---- phase 3: level-1, K16 GEMM1 + K32 GEMM2 (all frags prefetched) ----
  {
    #pragma unroll
    for (int k2=0;k2<2;k2++){
      const int u = su*2 + k2;
      if (u >= 15) break;
      const int base_u = (u<9) ? (u/3)*4 : ((u<12) ? 12 : (u-12)*4);
      float4 b2v = *(const float4*)(P + OFF_b2P1 + u*16 + q*4);

      #pragma unroll 2
      for (int m=0;m<8;m++){
        // K16 B-frag: q0 -> in[0..3], q1 -> in[4..7], q2 -> {1,0,0,0}
        // (activates k=8 bias row), q3 -> zeros.
        const u32* ap = (q < 2) ? (l1in + (m*16 + c16)*XST + base_u + 2*q)
                                : (ONESp + (q-2)*2);
        half4 af = *(const half4*)ap;
        floatx4 acc[4];
        #pragma unroll
        for (int t=0;t<4;t++) acc[t] = (floatx4){0.f,0.f,0.f,0.f};
        #pragma unroll
        for (int t=0;t<4;t++)
          acc[t] = __builtin_amdgcn_mfma_f32_16x16x16f16(pf1c[k2][t], af, acc[t], 0,0,0);
        floatx4 oc = (floatx4){b2v.x, b2v.y, b2v.z, b2v.w};
        #pragma unroll
        for (int ks=0;ks<2;ks++){
          u32 aw[4];
          aw[0] = pkrelu(acc[2*ks  ][0], acc[2*ks  ][1]);
          aw[1] = pkrelu(acc[2*ks  ][2], acc[2*ks  ][3]);
          aw[2] = pkrelu(acc[2*ks+1][0], acc[2*ks+1][1]);
          aw[3] = pkrelu(acc[2*ks+1][2], acc[2*ks+1][3]);
          half8 haf; __builtin_memcpy(&haf, aw, 16);
          oc = __builtin_amdgcn_mfma_f32_16x16x32_f16(pw2f[k2][ks], haf, oc, 0,0,0);
        }
        if (q < 2){
          uint2 ov;
          ov.x = pkrelu(oc[0], oc[1]);
          ov.y = pkrelu(oc[2], oc[3]);
          *(uint2*)(obT + u*512 + (m*16 + c16)*4 + q*2) = ov;
        }
      }
    }
  }
  __syncthreads();

  // ---- phase 4: level-1 gates (dot2) + sparse mixing + towers ----
  if (w < 3){
    const int t = w;
    uint4 gw = *(const uint4*)(obT + (12+t)*512 + e*4);
    float lg[6];
    #pragma unroll
    for (int m=0;m<6;m++){
      const int o = OFF_G1W3 + (t*6+m)*4;
      float s = dot2(gw.x, wsU[o+0], 0.f);
      s = dot2(gw.y, wsU[o+1], s);
      s = dot2(gw.z, wsU[o+2], s);
      s = dot2(gw.w, wsU[o+3], s);
      lg[m] = s;
    }
    softmaxT<6>(lg);
    hv2 a01 = (hv2){0,0}, a23 = (hv2){0,0}, a45 = (hv2){0,0}, a67 = (hv2){0,0};
    #pragma unroll
    for (int i=0;i<6;i++){
      const int u = (i<3) ? (3*t + i) : (6 + i);
      uint4 ow = *(const uint4*)(obT + u*512 + e*4);
      __fp16 wh = (__fp16)lg[i];
      hv2 wp = (hv2){wh, wh};
      a01 = u2h(ow.x)*wp + a01;
      a23 = u2h(ow.y)*wp + a23;
      a45 = u2h(ow.z)*wp + a45;
      a67 = u2h(ow.w)*wp + a67;
    }
    float s = P[OFF_Tb + t];
    s = dot2(h2u(a01), wsU[OFF_TWH + t*4 + 0], s);
    s = dot2(h2u(a23), wsU[OFF_TWH + t*4 + 1], s);
    s = dot2(h2u(a45), wsU[OFF_TWH + t*4 + 2], s);
    s = dot2(h2u(a67), wsU[OFF_TWH + t*4 + 3], s);
    out[t*Btot + blockIdx.x*EPB + e] = 1.f/(1.f + __expf(-s));
  }
}

extern "C" void kernel_launch(void* const* d_in, const int* in_sizes, int n_in,
                              void* d_out, int out_size, void* d_ws, size_t ws_size,
                              hipStream_t stream)
{
  const float* emb = (const float*)d_in[0];
  const int* cat = (const int*)d_in[34];
  float* out = (float*)d_out;
  u32* wsU = (u32*)d_ws;
  float* wsF = (float*)d_ws;
  PSrc S;
  for (int k=0;k<33;k++) S.p[k] = (const float*)d_in[k+1];
  const int B = in_sizes[34] / 9;   // 131072

  cvt_kernel<<<(CVT_TOTAL+255)/256, 256, 0, stream>>>(S, wsU, wsF);
  ple_kernel<<<B/EPB, NT, 0, stream>>>(emb, cat, wsU, wsF, out, B);
}